// Round 20
// baseline (834.145 us; speedup 1.0000x reference)
//
#include <hip/hip_runtime.h>
#include <hip/hip_bf16.h>

typedef __bf16 bf16x8 __attribute__((ext_vector_type(8)));
typedef float  f32x4  __attribute__((ext_vector_type(4)));
typedef int    i32x4  __attribute__((ext_vector_type(4)));

#define BM 128
#define BN 128
#define THREADS 256

__device__ __forceinline__ void gload_lds16(const void* g, void* l) {
  __builtin_amdgcn_global_load_lds(
      (const __attribute__((address_space(1))) void*)g,
      (__attribute__((address_space(3))) void*)l, 16, 0, 0);
}

template<int N> __device__ __forceinline__ void vmwait() {
  if constexpr (N == 0)      asm volatile("s_waitcnt vmcnt(0)");
  else if constexpr (N == 4) asm volatile("s_waitcnt vmcnt(4)");
}

__device__ __forceinline__ void tile_barrier() {
  __builtin_amdgcn_sched_barrier(0);
  asm volatile("s_barrier");
  __builtin_amdgcn_sched_barrier(0);
}

// ---- FUSED prep (r19-verbatim): blocks [0,M) quantize x rows; rest convert W.
__global__ __launch_bounds__(256)
void prep_kernel(const float* __restrict__ x, signed char* __restrict__ xq,
                 float* __restrict__ sx, int* __restrict__ rowsum,
                 const int* __restrict__ w, const int* __restrict__ zp,
                 signed char* __restrict__ wq, int M, int K) {
  const int tid = threadIdx.x;
  if ((int)blockIdx.x < M) {
    const int row = blockIdx.x;
    const int wave = tid >> 6, lane = tid & 63;
    const float* xr = x + (long)row * K;
    __shared__ float smax[4];
    __shared__ int   ssum[4];

    float amax = 0.f;
    for (int i = tid * 16; i < K; i += 256 * 16) {
      #pragma unroll
      for (int j = 0; j < 4; ++j) {
        float4 v = *(const float4*)(xr + i + j * 4);
        amax = fmaxf(amax, fmaxf(fmaxf(fabsf(v.x), fabsf(v.y)),
                                 fmaxf(fabsf(v.z), fabsf(v.w))));
      }
    }
    #pragma unroll
    for (int m = 32; m >= 1; m >>= 1) amax = fmaxf(amax, __shfl_xor(amax, m));
    if (lane == 0) smax[wave] = amax;
    __syncthreads();
    const float m4 = fmaxf(fmaxf(smax[0], smax[1]), fmaxf(smax[2], smax[3]));
    const float scale = (m4 > 0.f) ? (m4 / 127.f) : 1.f;
    const float inv   = (m4 > 0.f) ? (127.f / m4) : 0.f;

    int lsum = 0;
    for (int i = tid * 16; i < K; i += 256 * 16) {
      union { signed char c[16]; int4 v; } u;
      #pragma unroll
      for (int j = 0; j < 4; ++j) {
        float4 v = *(const float4*)(xr + i + j * 4);
        int q0 = __float2int_rn(v.x * inv), q1 = __float2int_rn(v.y * inv);
        int q2 = __float2int_rn(v.z * inv), q3 = __float2int_rn(v.w * inv);
        u.c[j*4+0] = (signed char)q0; u.c[j*4+1] = (signed char)q1;
        u.c[j*4+2] = (signed char)q2; u.c[j*4+3] = (signed char)q3;
        lsum += q0 + q1 + q2 + q3;
      }
      *(int4*)(xq + (long)row * K + i) = u.v;
    }
    #pragma unroll
    for (int m = 32; m >= 1; m >>= 1) lsum += __shfl_xor(lsum, m);
    if (lane == 0) ssum[wave] = lsum;
    __syncthreads();
    if (tid == 0) {
      rowsum[row] = ssum[0] + ssum[1] + ssum[2] + ssum[3];
      sx[row] = scale;
    }
  } else {
    const long i = ((long)(blockIdx.x - M) * 4096) + tid * 16;
    const int z = zp[i / K];
    union { signed char c[16]; int4 v; } u;
    #pragma unroll
    for (int j = 0; j < 4; ++j) {
      int4 a = *(const int4*)(w + i + j * 4);
      int q0 = min(127, max(-128, a.x - z)), q1 = min(127, max(-128, a.y - z));
      int q2 = min(127, max(-128, a.z - z)), q3 = min(127, max(-128, a.w - z));
      u.c[j*4+0] = (signed char)q0; u.c[j*4+1] = (signed char)q1;
      u.c[j*4+2] = (signed char)q2; u.c[j*4+3] = (signed char)q3;
    }
    *(int4*)(wq + i) = u.v;
  }
}

// ====== int8 128x128 GEMM, split-stage counted-vmcnt, 32 KiB LDS ======
// r18/r19 ledger: per tile-instance 1343-1460 cy vs LDS-pipe floor ~1150;
// residual = the per-tile vmcnt(0) FULL DRAIN that single-buffering puts on
// the critical path. Fix while keeping 4 blocks/CU (the proven TLP regime):
// compute in BK=64 halves, LDS = As[2][128*64]+Bs[2][128*64] = 32 KiB; K is
// staged in 128-B PAIRS so both 64-B halves of each cache line are fetched
// within one pair-period (~1200 cy, L2-resident -> full-line HBM unlike r15).
// Steady pair p:  compute h0 | bar | stage h0(p+1) vmcnt(4) bar |
//                 compute h1 | bar | stage h1(p+1) vmcnt(4) bar
// vmcnt(4) retires exactly the half being published (4 loads/wave/half);
// stages issue ~600 cy before use -> drain off critical path; vmcnt never 0
// in steady state. WAR: every ds_read feeds an MFMA above the preceding
// barrier. Swizzle: r15's verified 64-B-row involution (slot' = slot ^
// ((row>>1)&3); stage source slot (l&3)^((l>>3)&3); read rdx =
// (ksl^((rsel>>1)&3))<<4). Patch/XCD mapping + epilogue = r18 verbatim.
__global__ __launch_bounds__(THREADS, 3)
void qlin_gemm_i8(const signed char* __restrict__ A, const signed char* __restrict__ B,
                  const float* __restrict__ sx, const int* __restrict__ rowsum,
                  const int* __restrict__ zp,
                  const float* __restrict__ scale, const float* __restrict__ bias,
                  float* __restrict__ C, int M, int N, int K) {
  __shared__ alignas(16) signed char As[2][BM * 64];   // 2 x 8 KiB
  __shared__ alignas(16) signed char Bs[2][BN * 64];   // 2 x 8 KiB

  const int tid  = threadIdx.x;
  const int wave = tid >> 6;
  const int lane = tid & 63;
  const int wm = wave >> 1, wn = wave & 1;       // 2x2 waves; per-wave 64x64

  const int bid = blockIdx.x, nwg = gridDim.x;
  const int ntn = N / BN, ntm = M / BM;
  long tm, tn;
  if ((nwg & 7) == 0 && (ntm & 7) == 0 && (ntn & 7) == 0 &&
      (nwg >> 3) == (ntm >> 3) * ntn) {
    const int xcd = bid & 7;
    const int l   = bid >> 3;
    const int R   = ntm >> 3;
    const int ps  = R << 3;
    const int w   = l % ps;
    tm = (long)xcd * R + (w % R);
    tn = (long)(l / ps) * 8 + (w / R);
  } else {
    tm = bid / ntn; tn = bid % ntn;
  }
  const long row0 = tm * BM;
  const long col0 = tn * BN;

  const signed char* Ag = A + row0 * (long)K;
  const signed char* Bg = B + col0 * (long)K;

  // staging (per half h): wave w covers rows [32w, 32w+32) as 2 instrs of
  // 16 rows x 64 B. HW: lane l -> dest + l*16 = (row +(l>>2), slot l&3).
  const int srow = lane >> 2;                              // row within 16
  const int kswz = ((lane & 3) ^ ((lane >> 3) & 3)) * 16;  // pre-swizzled bytes

#define STAGE_A(h, c, kt) gload_lds16(                                        \
    Ag + (long)(32*wave + 16*(c) + srow) * K + (kt) + (h)*64 + kswz,          \
    &As[h][2048*wave + 1024*(c)])
#define STAGE_B(h, c, kt) gload_lds16(                                        \
    Bg + (long)(32*wave + 16*(c) + srow) * K + (kt) + (h)*64 + kswz,          \
    &Bs[h][2048*wave + 1024*(c)])
#define STAGE4(h, kt) { STAGE_A(h,0,kt); STAGE_A(h,1,kt); \
                        STAGE_B(h,0,kt); STAGE_B(h,1,kt); }

  const int rsel = lane & 15;
  const int ksl  = lane >> 4;                          // 16B k-slot (K=64)
  const int rdx  = ((ksl ^ ((rsel >> 1) & 3)) << 4);   // swizzled slot offset

  i32x4 acc[4][4] = {};

#define AF_READ(h, m) \
  (*(const i32x4*)&As[h][(wm*64 + (m)*16 + rsel)*64 + rdx])

#define COMPUTE(h)                                                             \
  {                                                                            \
    __builtin_amdgcn_s_setprio(1);                                             \
    i32x4 bf[4];                                                               \
    _Pragma("unroll")                                                          \
    for (int n = 0; n < 4; ++n)                                                \
      bf[n] = *(const i32x4*)&Bs[h][(wn*64 + n*16 + rsel)*64 + rdx];           \
    i32x4 afp0, afp1;                                                          \
    afp0 = AF_READ(h, 0);                                                      \
    _Pragma("unroll")                                                          \
    for (int f = 0; f < 4; ++f) {                                              \
      if (f < 3) {                                                             \
        if (f & 1) afp0 = AF_READ(h, f + 1);                                   \
        else       afp1 = AF_READ(h, f + 1);                                   \
      }                                                                        \
      _Pragma("unroll")                                                        \
      for (int n = 0; n < 4; ++n)                                              \
        acc[f][n] = __builtin_amdgcn_mfma_i32_16x16x64_i8(                     \
            (f & 1) ? afp1 : afp0, bf[n], acc[f][n], 0, 0, 0);                 \
    }                                                                          \
    __builtin_amdgcn_s_setprio(0);                                             \
  }

  const int NP = K / 128;   // pairs; >= 2 (guarded by launcher)

  // Prologue: stage pair 0 (h0 then h1); land h0; h1 stays in flight.
  STAGE4(0, 0)
  STAGE4(1, 0)
  vmwait<4>();                   // h0's 4 retired; h1's 4 in flight
  tile_barrier();

  for (int p = 0; p < NP - 1; ++p) {
    const long ktn = (long)(p + 1) * 128;
    COMPUTE(0)
    tile_barrier();              // (a) h0 reads done
    STAGE4(0, ktn)               // WAR-safe
    vmwait<4>();                 // retires h1(p); h0(p+1) in flight
    tile_barrier();              // (b) publish h1(p)
    COMPUTE(1)
    tile_barrier();              // (c) h1 reads done
    STAGE4(1, ktn)
    vmwait<4>();                 // retires h0(p+1); h1(p+1) in flight
    tile_barrier();              // (d) publish h0(p+1)
  }
  // Tail pair NP-1: h0 published; h1 in flight.
  COMPUTE(0)
  vmwait<0>();                   // drain h1
  tile_barrier();                // publish h1
  COMPUTE(1)
#undef COMPUTE
#undef AF_READ
#undef STAGE4
#undef STAGE_A
#undef STAGE_B

  // Epilogue. C/D layout: col = lane&15, row = (lane>>4)*4 + j.
  // out = sx*sw*(acc - zp*rowsum) + bias  (zp exact).
  float swv[4], bvv[4]; int zpv[4];
  #pragma unroll
  for (int n = 0; n < 4; ++n) {
    const long gcol = col0 + wn * 64 + n * 16 + rsel;
    swv[n] = scale[gcol];
    bvv[n] = bias[gcol];
    zpv[n] = zp[gcol];
  }
  #pragma unroll
  for (int m = 0; m < 4; ++m) {
    const long growb = row0 + wm * 64 + m * 16 + ksl * 4;
    #pragma unroll
    for (int j = 0; j < 4; ++j) {
      const long grow = growb + j;
      const float sxv = sx[grow];
      const int   rsv = rowsum[grow];
      float* orow = C + grow * (long)N;
      #pragma unroll
      for (int n = 0; n < 4; ++n) {
        const long gcol = col0 + wn * 64 + n * 16 + rsel;
        orow[gcol] = (float)(acc[m][n][j] - zpv[n] * rsv) * (sxv * swv[n]) + bvv[n];
      }
    }
  }
}

// ---- fallback (ws too small / odd shape): reg-staged 128x128 bf16, inline dequant ----
__global__ __launch_bounds__(256)
void qlin_gemm_small(const float* __restrict__ Af, const int* __restrict__ Bi,
                     const int* __restrict__ zp,
                     const float* __restrict__ scale, const float* __restrict__ bias,
                     float* __restrict__ C, int M, int N, int K) {
  __shared__ alignas(16) __bf16 As[128 * 64];
  __shared__ alignas(16) __bf16 Bs[128 * 64];
  const int tid = threadIdx.x, wave = tid >> 6, lane = tid & 63;
  int bid = blockIdx.x, nwg = gridDim.x, swz = bid;
  if ((nwg & 7) == 0) swz = (bid & 7) * (nwg >> 3) + (bid >> 3);
  const int ntn = N / 128;
  const long row0 = (long)(swz / ntn) * 128, col0 = (long)(swz % ntn) * 128;
  const int wr = wave >> 1, wc = wave & 1;
  f32x4 acc[4][4] = {};
  for (int kt = 0; kt < K; kt += 64) {
    #pragma unroll
    for (int i = 0; i < 4; ++i) {
      const int flat = i * 2048 + tid * 8;
      const int r = flat >> 6, cc = flat & 63;
      const int wcc = ((cc >> 3) ^ (r & 7)) << 3;
      const float* g = Af + (row0 + r) * (long)K + kt + cc;
      float4 f0 = *(const float4*)g; float4 f1 = *(const float4*)(g + 4);
      bf16x8 v;
      v[0]=(__bf16)f0.x; v[1]=(__bf16)f0.y; v[2]=(__bf16)f0.z; v[3]=(__bf16)f0.w;
      v[4]=(__bf16)f1.x; v[5]=(__bf16)f1.y; v[6]=(__bf16)f1.z; v[7]=(__bf16)f1.w;
      *(bf16x8*)(As + r * 64 + wcc) = v;
    }
    #pragma unroll
    for (int i = 0; i < 4; ++i) {
      const int flat = i * 2048 + tid * 8;
      const int r = flat >> 6, cc = flat & 63;
      const int wcc = ((cc >> 3) ^ (r & 7)) << 3;
      const long grow = col0 + r;
      const int z = zp[grow];
      const int* g = Bi + grow * (long)K + kt + cc;
      int4 a = *(const int4*)g; int4 b = *(const int4*)(g + 4);
      bf16x8 v;
      v[0]=(__bf16)(float)(a.x-z); v[1]=(__bf16)(float)(a.y-z);
      v[2]=(__bf16)(float)(a.z-z); v[3]=(__bf16)(float)(a.w-z);
      v[4]=(__bf16)(float)(b.x-z); v[5]=(__bf16)(float)(b.y-z);
      v[6]=(__bf16)(float)(b.z-z); v[7]=(__bf16)(float)(b.w-z);
      *(bf16x8*)(Bs + r * 64 + wcc) = v;
    }
    __syncthreads();
    #pragma unroll
    for (int kk = 0; kk < 2; ++kk) {
      bf16x8 af[4], bfr[4];
      const int rs = lane & 15, ks = kk * 4 + (lane >> 4);
      const int rd = (ks ^ (lane & 7)) << 3;
      #pragma unroll
      for (int m = 0; m < 4; ++m) af[m] = *(const bf16x8*)(As + (wr*64 + m*16 + rs)*64 + rd);
      #pragma unroll
      for (int n = 0; n < 4; ++n) bfr[n] = *(const bf16x8*)(Bs + (wc*64 + n*16 + rs)*64 + rd);
      #pragma unroll
      for (int m = 0; m < 4; ++m)
        #pragma unroll
        for (int n = 0; n < 4; ++n)
          acc[m][n] = __builtin_amdgcn_mfma_f32_16x16x32_bf16(af[m], bfr[n], acc[m][n], 0, 0, 0);
    }
    __syncthreads();
  }
  #pragma unroll
  for (int m = 0; m < 4; ++m) {
    const long grow = row0 + wr * 64 + m * 16 + ((lane >> 4) << 2);
    #pragma unroll
    for (int n = 0; n < 4; ++n) {
      const long gcol = col0 + wc * 64 + n * 16 + (lane & 15);
      const float s = scale[gcol], bb2 = bias[gcol];
      float* o = C + grow * (long)N + gcol;
      #pragma unroll
      for (int j = 0; j < 4; ++j) o[(long)j * N] = acc[m][n][j] * s + bb2;
    }
  }
}

extern "C" void kernel_launch(void* const* d_in, const int* in_sizes, int n_in,
                              void* d_out, int out_size, void* d_ws, size_t ws_size,
                              hipStream_t stream) {
  const float* x    = (const float*)d_in[0];
  const int*   wint = (const int*)d_in[1];
  const float* wsc  = (const float*)d_in[2];
  const int*   wzp  = (const int*)d_in[3];
  const float* bias = (const float*)d_in[4];
  float* out = (float*)d_out;

  const int N = in_sizes[4];            // 16384 (OUT)
  const int K = in_sizes[1] / N;        // 4096  (IN)
  const int M = in_sizes[0] / K;        // 8192  (B*S)

  const size_t xqb = (size_t)M * K;             // int8 x
  const size_t wqb = (size_t)N * K;             // int8 w
  const size_t sxb = (size_t)M * sizeof(float);
  const size_t rsb = (size_t)M * sizeof(int);
  const long nk = (long)N * K;

  if (ws_size >= xqb + wqb + sxb + rsb && (M % BM) == 0 && (N % BN) == 0 &&
      (K % 128) == 0 && (K % 4096) == 0 && (K / 128) >= 2 && (nk % 4096) == 0) {
    signed char* xq = (signed char*)d_ws;
    signed char* wq = xq + xqb;
    float* sx  = (float*)(wq + wqb);
    int* rsum  = (int*)((char*)sx + sxb);
    const int wblocks = (int)(nk / 4096);
    prep_kernel<<<M + wblocks, 256, 0, stream>>>(x, xq, sx, rsum,
                                                 wint, wzp, wq, M, K);
    const int grid = (M / BM) * (N / BN); // 64 * 128 = 8192
    qlin_gemm_i8<<<grid, THREADS, 0, stream>>>(xq, wq, sx, rsum, wzp, wsc, bias,
                                               out, M, N, K);
  } else {
    const int grid = (M / 128) * (N / 128);
    qlin_gemm_small<<<grid, 256, 0, stream>>>(x, wint, wzp, wsc, bias, out, M, N, K);
  }
}

// Round 21
// 687.879 us; speedup vs baseline: 1.2126x; 1.2126x over previous
//
#include <hip/hip_runtime.h>
#include <hip/hip_bf16.h>

typedef __bf16 bf16x8 __attribute__((ext_vector_type(8)));
typedef float  f32x4  __attribute__((ext_vector_type(4)));
typedef int    i32x4  __attribute__((ext_vector_type(4)));

#define BM 128
#define BN 128
#define BK 128          // full 128-B rows (r15 lesson)
#define THREADS 256

__device__ __forceinline__ void gload_lds16(const void* g, void* l) {
  __builtin_amdgcn_global_load_lds(
      (const __attribute__((address_space(1))) void*)g,
      (__attribute__((address_space(3))) void*)l, 16, 0, 0);
}

__device__ __forceinline__ void vmwait0() { asm volatile("s_waitcnt vmcnt(0)"); }

__device__ __forceinline__ void tile_barrier() {
  __builtin_amdgcn_sched_barrier(0);
  asm volatile("s_barrier");
  __builtin_amdgcn_sched_barrier(0);
}

// ---- FUSED prep: blocks [0,M) quantize x rows; blocks [M, M+NK/4096) convert W.
__global__ __launch_bounds__(256)
void prep_kernel(const float* __restrict__ x, signed char* __restrict__ xq,
                 float* __restrict__ sx, int* __restrict__ rowsum,
                 const int* __restrict__ w, const int* __restrict__ zp,
                 signed char* __restrict__ wq, int M, int K) {
  const int tid = threadIdx.x;
  if ((int)blockIdx.x < M) {
    // ---- x-row quantization (one block per row) ----
    const int row = blockIdx.x;
    const int wave = tid >> 6, lane = tid & 63;
    const float* xr = x + (long)row * K;
    __shared__ float smax[4];
    __shared__ int   ssum[4];

    float amax = 0.f;
    for (int i = tid * 16; i < K; i += 256 * 16) {
      #pragma unroll
      for (int j = 0; j < 4; ++j) {
        float4 v = *(const float4*)(xr + i + j * 4);
        amax = fmaxf(amax, fmaxf(fmaxf(fabsf(v.x), fabsf(v.y)),
                                 fmaxf(fabsf(v.z), fabsf(v.w))));
      }
    }
    #pragma unroll
    for (int m = 32; m >= 1; m >>= 1) amax = fmaxf(amax, __shfl_xor(amax, m));
    if (lane == 0) smax[wave] = amax;
    __syncthreads();
    const float m4 = fmaxf(fmaxf(smax[0], smax[1]), fmaxf(smax[2], smax[3]));
    const float scale = (m4 > 0.f) ? (m4 / 127.f) : 1.f;
    const float inv   = (m4 > 0.f) ? (127.f / m4) : 0.f;

    int lsum = 0;
    for (int i = tid * 16; i < K; i += 256 * 16) {
      union { signed char c[16]; int4 v; } u;
      #pragma unroll
      for (int j = 0; j < 4; ++j) {
        float4 v = *(const float4*)(xr + i + j * 4);
        int q0 = __float2int_rn(v.x * inv), q1 = __float2int_rn(v.y * inv);
        int q2 = __float2int_rn(v.z * inv), q3 = __float2int_rn(v.w * inv);
        u.c[j*4+0] = (signed char)q0; u.c[j*4+1] = (signed char)q1;
        u.c[j*4+2] = (signed char)q2; u.c[j*4+3] = (signed char)q3;
        lsum += q0 + q1 + q2 + q3;
      }
      *(int4*)(xq + (long)row * K + i) = u.v;
    }
    #pragma unroll
    for (int m = 32; m >= 1; m >>= 1) lsum += __shfl_xor(lsum, m);
    if (lane == 0) ssum[wave] = lsum;
    __syncthreads();
    if (tid == 0) {
      rowsum[row] = ssum[0] + ssum[1] + ssum[2] + ssum[3];
      sx[row] = scale;
    }
  } else {
    // ---- weight conversion: 4096 contiguous elems per block ----
    const long i = ((long)(blockIdx.x - M) * 4096) + tid * 16;
    const int z = zp[i / K];   // 16-elem chunk never crosses a row (K%16==0)
    union { signed char c[16]; int4 v; } u;
    #pragma unroll
    for (int j = 0; j < 4; ++j) {
      int4 a = *(const int4*)(w + i + j * 4);
      int q0 = min(127, max(-128, a.x - z)), q1 = min(127, max(-128, a.y - z));
      int q2 = min(127, max(-128, a.z - z)), q3 = min(127, max(-128, a.w - z));
      u.c[j*4+0] = (signed char)q0; u.c[j*4+1] = (signed char)q1;
      u.c[j*4+2] = (signed char)q2; u.c[j*4+3] = (signed char)q3;
    }
    *(int4*)(wq + i) = u.v;
  }
}

// ====== int8 128x128 GEMM, BK=128, single-buffer, ~4 blocks/CU ======
// r18/r19-verbatim — the measured minimum-sync configuration (plateau):
// single-buffer 32 KiB LDS + 128 combined regs (64 VGPR + 64 AGPR) -> 4
// independent barrier groups/CU give the overlap (m114 TLP); XCD-stripe +
// 8x8-patch mapping keeps the working set L2-resident (FETCH 0.75 GB).
// r20 tested counted-vmcnt split-staging (8 sync/128-K): regressed 25% —
// the residual IS barrier cost; both directions off this point are worse.
// Ledger: 573-627 us, MfmaUtil ~50%, LDS 73 B/cy, HBM 2.3 TB/s.
__global__ __launch_bounds__(THREADS, 3)
void qlin_gemm_i8(const signed char* __restrict__ A, const signed char* __restrict__ B,
                  const float* __restrict__ sx, const int* __restrict__ rowsum,
                  const int* __restrict__ zp,
                  const float* __restrict__ scale, const float* __restrict__ bias,
                  float* __restrict__ C, int M, int N, int K) {
  __shared__ alignas(16) signed char As[BM * BK];   // 16 KiB
  __shared__ alignas(16) signed char Bs[BN * BK];   // 16 KiB

  const int tid  = threadIdx.x;
  const int wave = tid >> 6;
  const int lane = tid & 63;
  const int wm = wave >> 1, wn = wave & 1;       // 2x2 waves; per-wave 64x64

  const int bid = blockIdx.x, nwg = gridDim.x;
  const int ntn = N / BN, ntm = M / BM;
  long tm, tn;
  if ((nwg & 7) == 0 && (ntm & 7) == 0 && (ntn & 7) == 0 &&
      (nwg >> 3) == (ntm >> 3) * ntn) {
    // XCD-chunked stripe (R=ntm/8 rows x ntn cols) + 8-col patches.
    const int xcd = bid & 7;
    const int l   = bid >> 3;            // local index within stripe
    const int R   = ntm >> 3;            // stripe rows
    const int ps  = R << 3;              // patch size = R*8 blocks
    const int w   = l % ps;
    tm = (long)xcd * R + (w % R);
    tn = (long)(l / ps) * 8 + (w / R);
  } else {
    tm = bid / ntn; tn = bid % ntn;
  }
  const long row0 = tm * BM;
  const long col0 = tn * BN;

  const signed char* Ag = A + row0 * (long)K;
  const signed char* Bg = B + col0 * (long)K;

  // staging: chunk c = rows [c*32, c*32+32); wave w covers rows c*32+w*8..+8
  // (1 KiB per instr). HW: lane l -> base + l*16 = (row w*8+(l>>3), slot l&7).
  const int srow = wave * 8 + (lane >> 3);              // row within chunk
  const int kswz = ((lane & 7) ^ (lane >> 3)) * 16;     // pre-swizzled bytes

#define STAGE_A(c, kt) gload_lds16(Ag + (long)((c)*32 + srow) * K + (kt) + kswz, \
                                   &As[(c)*4096 + wave*1024])
#define STAGE_B(c, kt) gload_lds16(Bg + (long)((c)*32 + srow) * K + (kt) + kswz, \
                                   &Bs[(c)*4096 + wave*1024])
#define STAGE8(kt) { STAGE_B(0,kt); STAGE_B(1,kt); STAGE_B(2,kt); STAGE_B(3,kt); \
                     STAGE_A(0,kt); STAGE_A(1,kt); STAGE_A(2,kt); STAGE_A(3,kt); }

  const int rsel = lane & 15;     // fragment row (within 16)
  const int ksl  = lane >> 4;     // 0..3 -> 16B k-slot within a 64-elem half
  const int lan7 = lane & 7;      // == frag-row & 7 (bases are multiples of 16)

  i32x4 acc[4][4] = {};
  i32x4 bf[4][2];                 // B frags [n][kk]

#define AF_READ(m, kk)                                                          \
  (*(const i32x4*)&As[(wm*64 + (m)*16 + rsel)*BK                                \
                      + (((((kk)<<2)+ksl) ^ lan7) << 4)])

  const int NT = K / BK;   // 32 for this shape

  for (int t = 0; t < NT; ++t) {
    const long kt = (long)t * BK;
    STAGE8(kt)
    vmwait0();
    tile_barrier();          // all waves' stages landed

    __builtin_amdgcn_s_setprio(1);
    #pragma unroll
    for (int n = 0; n < 4; ++n)
      #pragma unroll
      for (int kk = 0; kk < 2; ++kk)
        bf[n][kk] = *(const i32x4*)&Bs[(wn*64 + n*16 + rsel)*BK
                                       + ((((kk<<2)+ksl) ^ lan7) << 4)];
    i32x4 afp0, afp1;
    afp0 = AF_READ(0, 0);
    #pragma unroll
    for (int f = 0; f < 8; ++f) {
      const int m = f & 3, kk = f >> 2;
      if (f < 7) {
        const int m2 = (f + 1) & 3, kk2 = (f + 1) >> 2;
        if (f & 1) afp0 = AF_READ(m2, kk2);
        else       afp1 = AF_READ(m2, kk2);
      }
      #pragma unroll
      for (int n = 0; n < 4; ++n)
        acc[m][n] = __builtin_amdgcn_mfma_i32_16x16x64_i8(
            (f & 1) ? afp1 : afp0, bf[n][kk], acc[m][n], 0, 0, 0);
    }
    __builtin_amdgcn_s_setprio(0);
    tile_barrier();          // WAR: reads done before next stage overwrites
  }
#undef AF_READ
#undef STAGE8
#undef STAGE_A
#undef STAGE_B

  // Epilogue. C/D layout (dtype-independent, m121-128): col = lane&15,
  // row = (lane>>4)*4 + j.  out = sx*sw*(acc - zp*rowsum) + bias.
  float swv[4], bvv[4]; int zpv[4];
  #pragma unroll
  for (int n = 0; n < 4; ++n) {
    const long gcol = col0 + wn * 64 + n * 16 + rsel;
    swv[n] = scale[gcol];
    bvv[n] = bias[gcol];
    zpv[n] = zp[gcol];
  }
  #pragma unroll
  for (int m = 0; m < 4; ++m) {
    const long growb = row0 + wm * 64 + m * 16 + ksl * 4;
    #pragma unroll
    for (int j = 0; j < 4; ++j) {
      const long grow = growb + j;
      const float sxv = sx[grow];
      const int   rsv = rowsum[grow];
      float* orow = C + grow * (long)N;
      #pragma unroll
      for (int n = 0; n < 4; ++n) {
        const long gcol = col0 + wn * 64 + n * 16 + rsel;
        orow[gcol] = (float)(acc[m][n][j] - zpv[n] * rsv) * (sxv * swv[n]) + bvv[n];
      }
    }
  }
}

// ---- fallback (ws too small / odd shape): reg-staged 128x128 bf16, inline dequant ----
__global__ __launch_bounds__(256)
void qlin_gemm_small(const float* __restrict__ Af, const int* __restrict__ Bi,
                     const int* __restrict__ zp,
                     const float* __restrict__ scale, const float* __restrict__ bias,
                     float* __restrict__ C, int M, int N, int K) {
  __shared__ alignas(16) __bf16 As[128 * 64];
  __shared__ alignas(16) __bf16 Bs[128 * 64];
  const int tid = threadIdx.x, wave = tid >> 6, lane = tid & 63;
  int bid = blockIdx.x, nwg = gridDim.x, swz = bid;
  if ((nwg & 7) == 0) swz = (bid & 7) * (nwg >> 3) + (bid >> 3);
  const int ntn = N / 128;
  const long row0 = (long)(swz / ntn) * 128, col0 = (long)(swz % ntn) * 128;
  const int wr = wave >> 1, wc = wave & 1;
  f32x4 acc[4][4] = {};
  for (int kt = 0; kt < K; kt += 64) {
    #pragma unroll
    for (int i = 0; i < 4; ++i) {
      const int flat = i * 2048 + tid * 8;
      const int r = flat >> 6, cc = flat & 63;
      const int wcc = ((cc >> 3) ^ (r & 7)) << 3;
      const float* g = Af + (row0 + r) * (long)K + kt + cc;
      float4 f0 = *(const float4*)g; float4 f1 = *(const float4*)(g + 4);
      bf16x8 v;
      v[0]=(__bf16)f0.x; v[1]=(__bf16)f0.y; v[2]=(__bf16)f0.z; v[3]=(__bf16)f0.w;
      v[4]=(__bf16)f1.x; v[5]=(__bf16)f1.y; v[6]=(__bf16)f1.z; v[7]=(__bf16)f1.w;
      *(bf16x8*)(As + r * 64 + wcc) = v;
    }
    #pragma unroll
    for (int i = 0; i < 4; ++i) {
      const int flat = i * 2048 + tid * 8;
      const int r = flat >> 6, cc = flat & 63;
      const int wcc = ((cc >> 3) ^ (r & 7)) << 3;
      const long grow = col0 + r;
      const int z = zp[grow];
      const int* g = Bi + grow * (long)K + kt + cc;
      int4 a = *(const int4*)g; int4 b = *(const int4*)(g + 4);
      bf16x8 v;
      v[0]=(__bf16)(float)(a.x-z); v[1]=(__bf16)(float)(a.y-z);
      v[2]=(__bf16)(float)(a.z-z); v[3]=(__bf16)(float)(a.w-z);
      v[4]=(__bf16)(float)(b.x-z); v[5]=(__bf16)(float)(b.y-z);
      v[6]=(__bf16)(float)(b.z-z); v[7]=(__bf16)(float)(b.w-z);
      *(bf16x8*)(Bs + r * 64 + wcc) = v;
    }
    __syncthreads();
    #pragma unroll
    for (int kk = 0; kk < 2; ++kk) {
      bf16x8 af[4], bfr[4];
      const int rs = lane & 15, ks = kk * 4 + (lane >> 4);
      const int rd = (ks ^ (lane & 7)) << 3;
      #pragma unroll
      for (int m = 0; m < 4; ++m) af[m] = *(const bf16x8*)(As + (wr*64 + m*16 + rs)*64 + rd);
      #pragma unroll
      for (int n = 0; n < 4; ++n) bfr[n] = *(const bf16x8*)(Bs + (wc*64 + n*16 + rs)*64 + rd);
      #pragma unroll
      for (int m = 0; m < 4; ++m)
        #pragma unroll
        for (int n = 0; n < 4; ++n)
          acc[m][n] = __builtin_amdgcn_mfma_f32_16x16x32_bf16(af[m], bfr[n], acc[m][n], 0, 0, 0);
    }
    __syncthreads();
  }
  #pragma unroll
  for (int m = 0; m < 4; ++m) {
    const long grow = row0 + wr * 64 + m * 16 + ((lane >> 4) << 2);
    #pragma unroll
    for (int n = 0; n < 4; ++n) {
      const long gcol = col0 + wc * 64 + n * 16 + (lane & 15);
      const float s = scale[gcol], bb2 = bias[gcol];
      float* o = C + grow * (long)N + gcol;
      #pragma unroll
      for (int j = 0; j < 4; ++j) o[(long)j * N] = acc[m][n][j] * s + bb2;
    }
  }
}

extern "C" void kernel_launch(void* const* d_in, const int* in_sizes, int n_in,
                              void* d_out, int out_size, void* d_ws, size_t ws_size,
                              hipStream_t stream) {
  const float* x    = (const float*)d_in[0];
  const int*   wint = (const int*)d_in[1];
  const float* wsc  = (const float*)d_in[2];
  const int*   wzp  = (const int*)d_in[3];
  const float* bias = (const float*)d_in[4];
  float* out = (float*)d_out;

  const int N = in_sizes[4];            // 16384 (OUT)
  const int K = in_sizes[1] / N;        // 4096  (IN)
  const int M = in_sizes[0] / K;        // 8192  (B*S)

  const size_t xqb = (size_t)M * K;             // int8 x
  const size_t wqb = (size_t)N * K;             // int8 w
  const size_t sxb = (size_t)M * sizeof(float);
  const size_t rsb = (size_t)M * sizeof(int);
  const int NT = K / BK;
  const long nk = (long)N * K;

  if (ws_size >= xqb + wqb + sxb + rsb && (M % BM) == 0 && (N % BN) == 0 &&
      (K % BK) == 0 && (K % 4096) == 0 && NT >= 2 && (nk % 4096) == 0) {
    signed char* xq = (signed char*)d_ws;
    signed char* wq = xq + xqb;
    float* sx  = (float*)(wq + wqb);
    int* rsum  = (int*)((char*)sx + sxb);
    const int wblocks = (int)(nk / 4096);
    prep_kernel<<<M + wblocks, 256, 0, stream>>>(x, xq, sx, rsum,
                                                 wint, wzp, wq, M, K);
    const int grid = (M / BM) * (N / BN); // 64 * 128 = 8192
    qlin_gemm_i8<<<grid, THREADS, 0, stream>>>(xq, wq, sx, rsum, wzp, wsc, bias,
                                               out, M, N, K);
  } else {
    const int grid = (M / 128) * (N / 128);
    qlin_gemm_small<<<grid, 256, 0, stream>>>(x, wint, wzp, wsc, bias, out, M, N, K);
  }
}